// Round 15
// baseline (481.404 us; speedup 1.0000x reference)
//
#include <hip/hip_runtime.h>

#define SEQ 16384
#define DIM 1280
#define NH 16
#define HD 80
#define NSEG 16
#define SEGL 1024

typedef __attribute__((ext_vector_type(8))) short bf16x8;
typedef __attribute__((ext_vector_type(4))) float f32x4;

__device__ inline unsigned short f2bf(float f){
  unsigned int x = __builtin_bit_cast(unsigned int, f);
  unsigned int r = (x + 0x7FFFu + ((x >> 16) & 1u)) >> 16;
  return (unsigned short)r;
}
__device__ inline float bf2f(unsigned short u){
  unsigned int x = ((unsigned int)u) << 16;
  return __builtin_bit_cast(float, x);
}
__device__ inline int cvtpk_bf16(float lo, float hi){
  int r;
  asm("v_cvt_pk_bf16_f32 %0, %1, %2" : "=v"(r) : "v"(lo), "v"(hi));
  return r;
}

__device__ inline void gload16(const unsigned short* g, unsigned short* l){
  __builtin_amdgcn_global_load_lds((const __attribute__((address_space(1))) void*)g,
                                   (__attribute__((address_space(3))) void*)l, 16, 0, 0);
}

// ---------------- fused pack f32 -> bf16 for all three tensors (one launch) ----------
__global__ __launch_bounds__(256) void pack3_kernel(const float* __restrict__ a,
    const float* __restrict__ b, const float* __restrict__ c,
    unsigned short* __restrict__ da, unsigned short* __restrict__ db,
    unsigned short* __restrict__ dc, int na, int nb){
  int i = blockIdx.x * 256 + threadIdx.x;
  const float* s; unsigned short* d; int j;
  if (i < na){ s = a; d = da; j = i; }
  else if (i < na + nb){ s = b; d = db; j = i - na; }
  else { s = c; d = dc; j = i - na - nb; }
  float4 v = ((const float4*)s)[j];
  ushort4 o;
  o.x = f2bf(v.x); o.y = f2bf(v.y); o.z = f2bf(v.z); o.w = f2bf(v.w);
  ((ushort4*)d)[j] = o;
}

// ---------------- 256x256 8-phase GEMM, PERSISTENT blocks  C = A * B^T (+bias) ---------
// grid = 256 (1 block/CU); each block loops over output tiles. The peeled last K-iter of
// tile j stages tile j+1's K-tiles 0/1 into the same buffer parities, so the counted-vmcnt
// pipeline never drains across tiles (cross-tile software-pipeline continuation).
// EPI==0: scatter bf16 into QKV[3][NH][SEQ][HD], with the V third written directly to
// Vt[NH][HD][SEQ] with the attention key-permutation. EPI==1: f32 row-major [M][N].
template<int EPI>
__global__ __launch_bounds__(512, 2) void gemm256_kernel(const unsigned short* __restrict__ A,
    const unsigned short* __restrict__ B, const float* __restrict__ bias,
    void* __restrict__ Cout, unsigned short* __restrict__ Vtg, int M, int N, int K){
  __shared__ __attribute__((aligned(16))) unsigned short As[2][16384];
  __shared__ __attribute__((aligned(16))) unsigned short Bs[2][16384];
  const int ntn = N >> 8;
  const int ntiles = (M >> 8) * ntn;       // 960 (gemm1) / 320 (gemm2); %8 == 0
  const int NITER = K >> 7;                // 10 for K=1280
  const int tid = threadIdx.x;
  const int wid = tid >> 6, l = tid & 63;
  const int lr = l & 15, lh = l >> 4;
  const int wrM = (wid >> 2) << 7;   // 0 / 128
  const int wcN = (wid & 3) << 6;    // 0 / 64 / 128 / 192

  const int srow = wid*8 + (l >> 3);
  const int scol = ((l & 7) ^ (l >> 3)) << 3;     // shorts
  const int sldsu = wid << 9;                     // shorts

  const int ck0 = (lh*8) ^ ((l & 7) << 3);
  const int ck1 = (32 + lh*8) ^ ((l & 7) << 3);
  const int raA = (wrM + lr) << 6;
  const int raB = (wcN + lr) << 6;

  f32x4 zf = {0.f,0.f,0.f,0.f};

#define STG_A(base, col, buf, h, q) gload16((base) + (size_t)((h)*128 + (q)*64 + srow)*K + (col) + scol, \
                                            &As[buf][(h)*8192 + (q)*4096 + sldsu])
#define STG_B(base, col, buf, h, q) gload16((base) + (size_t)((h)*128 + (q)*64 + srow)*K + (col) + scol, \
                                            &Bs[buf][(h)*8192 + (q)*4096 + sldsu])
#define RD_A(b, MOFF) \
  _Pragma("unroll") \
  for (int mi=0; mi<4; ++mi){ \
    a[0][mi] = *(const bf16x8*)&As[b][raA + ((MOFF)+mi)*1024 + ck0]; \
    a[1][mi] = *(const bf16x8*)&As[b][raA + ((MOFF)+mi)*1024 + ck1]; }
#define RD_B(b, NOFF, BREG) \
  _Pragma("unroll") \
  for (int nj=0; nj<2; ++nj){ \
    BREG[0][nj] = *(const bf16x8*)&Bs[b][raB + ((NOFF)+nj)*1024 + ck0]; \
    BREG[1][nj] = *(const bf16x8*)&Bs[b][raB + ((NOFF)+nj)*1024 + ck1]; }
#define BAR() __builtin_amdgcn_s_barrier();
#define QMFMA(MB, NB, BREG) \
  __builtin_amdgcn_s_setprio(1); \
  _Pragma("unroll") \
  for (int mi=0; mi<4; ++mi){ \
    _Pragma("unroll") \
    for (int nj=0; nj<2; ++nj){ \
      acc[(MB)+mi][(NB)+nj] = __builtin_amdgcn_mfma_f32_16x16x32_bf16(a[0][mi], BREG[0][nj], acc[(MB)+mi][(NB)+nj], 0,0,0); \
      acc[(MB)+mi][(NB)+nj] = __builtin_amdgcn_mfma_f32_16x16x32_bf16(a[1][mi], BREG[1][nj], acc[(MB)+mi][(NB)+nj], 0,0,0); \
    } \
  } \
  __builtin_amdgcn_s_setprio(0); \
  __builtin_amdgcn_s_barrier();

  int tix = blockIdx.x;
  int swz = (tix & 7) * (ntiles >> 3) + (tix >> 3);
  int tm = (swz / ntn) << 8;
  int tn = (swz % ntn) << 8;
  const unsigned short* Ag = A + (size_t)tm * K;
  const unsigned short* Bg = B + (size_t)tn * K;

  // prologue (first tile only): stage K-tiles 0 and 1; drain tile 0, keep tile 1 in flight
  #pragma unroll
  for (int q=0;q<2;q++){ STG_A(Ag, 0, 0, 0, q); }
  #pragma unroll
  for (int q=0;q<2;q++){ STG_A(Ag, 0, 0, 1, q); }
  #pragma unroll
  for (int q=0;q<2;q++){ STG_B(Bg, 0, 0, 0, q); }
  #pragma unroll
  for (int q=0;q<2;q++){ STG_B(Bg, 0, 0, 1, q); }
  #pragma unroll
  for (int q=0;q<2;q++){ STG_B(Bg, 64, 1, 0, q); }
  #pragma unroll
  for (int q=0;q<2;q++){ STG_B(Bg, 64, 1, 1, q); }
  #pragma unroll
  for (int q=0;q<2;q++){ STG_A(Ag, 64, 1, 0, q); }
  #pragma unroll
  for (int q=0;q<2;q++){ STG_A(Ag, 64, 1, 1, q); }
  asm volatile("s_waitcnt vmcnt(8)" ::: "memory");
  __builtin_amdgcn_s_barrier();

  while (true){
    const bool hn = (tix + (int)gridDim.x) < ntiles;
    int tm2 = 0, tn2 = 0;
    const unsigned short* Agn = Ag;
    const unsigned short* Bgn = Bg;
    if (hn){
      int tix2 = tix + gridDim.x;
      int swz2 = (tix2 & 7) * (ntiles >> 3) + (tix2 >> 3);
      tm2 = (swz2 / ntn) << 8;
      tn2 = (swz2 % ntn) << 8;
      Agn = A + (size_t)tm2 * K;
      Bgn = B + (size_t)tn2 * K;
    }

    f32x4 acc[8][4];
    #pragma unroll
    for (int i=0;i<8;i++)
      #pragma unroll
      for (int j=0;j<4;j++) acc[i][j] = zf;

    // steady iterations: all stages target the CURRENT tile (T+2 -> buf0, T+3 -> buf1)
    for (int i=0; i<NITER-1; ++i){
      const int T = 2*i;
      bf16x8 a[2][4], bx[2][2], by[2][2];

      RD_B(0, 0, bx); RD_A(0, 0);
      BAR(); QMFMA(0, 0, bx);

      RD_B(0, 2, by);
      BAR(); QMFMA(0, 2, by);

      RD_A(0, 4);
      STG_B(Bg, (T+2)<<6, 0, 0, 0); STG_B(Bg, (T+2)<<6, 0, 0, 1);
      BAR(); QMFMA(4, 2, by);

      STG_B(Bg, (T+2)<<6, 0, 1, 0); STG_B(Bg, (T+2)<<6, 0, 1, 1);
      STG_A(Ag, (T+2)<<6, 0, 0, 0); STG_A(Ag, (T+2)<<6, 0, 0, 1);
      asm volatile("s_waitcnt vmcnt(6)" ::: "memory");
      BAR(); QMFMA(4, 0, bx);

      RD_B(1, 0, bx); RD_A(1, 0);
      STG_A(Ag, (T+2)<<6, 0, 1, 0); STG_A(Ag, (T+2)<<6, 0, 1, 1);
      BAR(); QMFMA(0, 0, bx);

      RD_B(1, 2, by);
      BAR(); QMFMA(0, 2, by);

      RD_A(1, 4);
      STG_B(Bg, (T+3)<<6, 1, 0, 0); STG_B(Bg, (T+3)<<6, 1, 0, 1);
      STG_B(Bg, (T+3)<<6, 1, 1, 0); STG_B(Bg, (T+3)<<6, 1, 1, 1);
      BAR(); QMFMA(4, 2, by);

      STG_A(Ag, (T+3)<<6, 1, 0, 0); STG_A(Ag, (T+3)<<6, 1, 0, 1);
      STG_A(Ag, (T+3)<<6, 1, 1, 0); STG_A(Ag, (T+3)<<6, 1, 1, 1);
      asm volatile("s_waitcnt vmcnt(8)" ::: "memory");
      BAR(); QMFMA(4, 0, bx);
    }

    // peeled last iteration: stages target NEXT tile's K-tiles 0 (buf0) and 1 (buf1)
    {
      bf16x8 a[2][4], bx[2][2], by[2][2];

      RD_B(0, 0, bx); RD_A(0, 0);
      BAR(); QMFMA(0, 0, bx);

      RD_B(0, 2, by);
      BAR(); QMFMA(0, 2, by);

      RD_A(0, 4);
      if (hn){ STG_B(Bgn, 0, 0, 0, 0); STG_B(Bgn, 0, 0, 0, 1); }
      BAR(); QMFMA(4, 2, by);

      if (hn){
        STG_B(Bgn, 0, 0, 1, 0); STG_B(Bgn, 0, 0, 1, 1);
        STG_A(Agn, 0, 0, 0, 0); STG_A(Agn, 0, 0, 0, 1);
        asm volatile("s_waitcnt vmcnt(6)" ::: "memory");
      } else {
        asm volatile("s_waitcnt vmcnt(0)" ::: "memory");
      }
      BAR(); QMFMA(4, 0, bx);

      RD_B(1, 0, bx); RD_A(1, 0);
      if (hn){ STG_A(Agn, 0, 0, 1, 0); STG_A(Agn, 0, 0, 1, 1); }
      BAR(); QMFMA(0, 0, bx);

      RD_B(1, 2, by);
      BAR(); QMFMA(0, 2, by);

      RD_A(1, 4);
      if (hn){
        STG_B(Bgn, 64, 1, 0, 0); STG_B(Bgn, 64, 1, 0, 1);
        STG_B(Bgn, 64, 1, 1, 0); STG_B(Bgn, 64, 1, 1, 1);
      }
      BAR(); QMFMA(4, 2, by);

      if (hn){
        STG_A(Agn, 64, 1, 0, 0); STG_A(Agn, 64, 1, 0, 1);
        STG_A(Agn, 64, 1, 1, 0); STG_A(Agn, 64, 1, 1, 1);
        asm volatile("s_waitcnt vmcnt(8)" ::: "memory");
      }
      BAR(); QMFMA(4, 0, bx);
    }

    // epilogue (no LDS use -> overlaps the in-flight prefetch of the next tile)
    #pragma unroll
    for (int nj=0;nj<4;nj++){
      int col = tn + wcN + nj*16 + lr;
      float bv = bias[col];
      if (EPI == 0){
        int which = col / DIM;           // uniform within the 16-col group
        int rem = col - which*DIM;
        int hh = rem / HD;
        int d = rem - hh*HD;
        if (which == 2){
          // fused V-transpose: write Vt[hh][d][s] with key-permutation per 64-block
          unsigned short* Vd = Vtg + ((size_t)hh * HD + d) * SEQ;
          #pragma unroll
          for (int mi=0;mi<8;mi++){
            int row0 = tm + wrM + mi*16 + lh*4;
            int g = (row0 >> 2) & 15;
            int pg = ((g>>3)<<3) + ((g&3)<<1) + ((g>>2)&1);
            int s = (row0 & ~63) + pg*4;
            unsigned int w0 = (unsigned int)cvtpk_bf16(acc[mi][nj][0]+bv, acc[mi][nj][1]+bv);
            unsigned int w1 = (unsigned int)cvtpk_bf16(acc[mi][nj][2]+bv, acc[mi][nj][3]+bv);
            uint2 ov = {w0, w1};
            *(uint2*)(Vd + s) = ov;
          }
        } else {
          unsigned short* Q = (unsigned short*)Cout;
          size_t base = (size_t)(which*NH + hh) * SEQ;
          #pragma unroll
          for (int mi=0;mi<8;mi++){
            #pragma unroll
            for (int r=0;r<4;r++){
              int row = tm + wrM + mi*16 + lh*4 + r;
              Q[(base + row)*HD + d] = f2bf(acc[mi][nj][r] + bv);
            }
          }
        }
      } else {
        float* C = (float*)Cout;
        #pragma unroll
        for (int mi=0;mi<8;mi++){
          #pragma unroll
          for (int r=0;r<4;r++){
            int row = tm + wrM + mi*16 + lh*4 + r;
            C[(size_t)row*N + col] = acc[mi][nj][r] + bv;
          }
        }
      }
    }

    if (!hn) break;
    tix += gridDim.x;
    tm = tm2; tn = tn2; Ag = Agn; Bg = Bgn;
  }

#undef STG_A
#undef STG_B
#undef RD_A
#undef RD_B
#undef BAR
#undef QMFMA
}

// ---------------- in-place RoPE, VECTORIZED: thread handles 8 (d, d+40) pairs ----------
// Q part pre-scaled by 1/sqrt(80)*log2(e). cos[s][d] == cos[s][d+40] by construction.
__global__ __launch_bounds__(256) void rope_kernel(unsigned short* __restrict__ QKV,
    const float* __restrict__ cosb, const float* __restrict__ sinb){
  unsigned int gid = blockIdx.x * 256 + threadIdx.x;   // 2*NH*SEQ*5 total
  int pc = gid % 5;
  unsigned int row = gid / 5;        // [(which*NH+h)*SEQ + s]
  int s = row % SEQ;
  int pd = pc * 8;
  float f = (row < (unsigned)(NH*SEQ)) ? (0.111803398874989485f * 1.4426950408889634f) : 1.0f;
  unsigned short* p = QKV + (size_t)row * HD;
  union { uint4 u4; unsigned short h[8]; } x1, x2, y1, y2;
  x1.u4 = *(const uint4*)(p + pd);
  x2.u4 = *(const uint4*)(p + pd + 40);
  float4 c0 = *(const float4*)(cosb + s*HD + pd);
  float4 c1 = *(const float4*)(cosb + s*HD + pd + 4);
  float4 s0 = *(const float4*)(sinb + s*HD + pd);
  float4 s1 = *(const float4*)(sinb + s*HD + pd + 4);
  float cc[8] = {c0.x,c0.y,c0.z,c0.w,c1.x,c1.y,c1.z,c1.w};
  float ss[8] = {s0.x,s0.y,s0.z,s0.w,s1.x,s1.y,s1.z,s1.w};
  #pragma unroll
  for (int j=0;j<8;j++){
    float a = bf2f(x1.h[j]), b = bf2f(x2.h[j]);
    y1.h[j] = f2bf((a*cc[j] - b*ss[j])*f);
    y2.h[j] = f2bf((b*cc[j] + a*ss[j])*f);
  }
  *(uint4*)(p + pd)      = y1.u4;
  *(uint4*)(p + pd + 40) = y2.u4;
}

// ---------------- flash attention, swapped operands; 8 waves x 16 q-rows = 128 q/block ----
// KVBLK=128: K staged PACKED [128][80] (straight contiguous copy); V staged [80][128]
// from pre-permuted Vt, XOR-swizzled at 16B granularity (c16 ^ (d&15), both sides).
// S = mfma(K, Q^T) -> C[key, q]; O = mfma(V^T, P^T) -> C[d, q]  (lane owns q-row lr)
// XCD-grouped block decode; deferred cross-lane row-sum.
__global__ __launch_bounds__(512) void attn_kernel(const unsigned short* __restrict__ QKV,
                                                   const unsigned short* __restrict__ Vt,
                                                   unsigned short* __restrict__ AO){
  int bid = blockIdx.x;
  int qt  = (bid >> 3) & 7;
  int g   = (bid & 7) * 32 + (bid >> 6);   // (seg,h) group, constant per XCD slot
  int h   = g & 15;
  int seg = g >> 4;
  int tid = threadIdx.x, wid = tid >> 6, l = tid & 63;
  int lr = l & 15, lh = l >> 4;
  const unsigned short* Qb = QKV + (size_t)(0*NH + h) * SEQ * HD;
  const unsigned short* Kb = QKV + (size_t)(1*NH + h) * SEQ * HD;
  const unsigned short* Vtb = Vt + (size_t)h * HD * SEQ;
  int q0 = seg*SEGL + qt*128;
  __shared__ __attribute__((aligned(16))) unsigned short Ksm[10240];  // [128][80] packed
  __shared__ __attribute__((aligned(16))) unsigned short Vtsm[10240]; // [80][128] swizzled
  bf16x8 qf[3];
  {
    const unsigned short* qp = Qb + (size_t)(q0 + wid*16 + lr) * HD;
    #pragma unroll
    for (int c=0;c<3;c++){
      int d0 = c*32 + lh*8;
      bf16x8 z = {0,0,0,0,0,0,0,0};
      qf[c] = (d0 < HD) ? *(const bf16x8*)(qp + d0) : z;
    }
  }
  f32x4 zf = {0.f,0.f,0.f,0.f};
  f32x4 o[5];
  #pragma unroll
  for (int dt=0;dt<5;dt++) o[dt] = zf;
  f32x4 lsumv = zf;
  float m = -1e30f;
  for (int kt=0; kt<8; kt++){
    int k0 = seg*SEGL + kt*128;
    const unsigned short* Ksrc = Kb + (size_t)k0 * HD;   // 128*80 shorts contiguous
    gload16(Ksrc + (wid*64 + l)*8,        &Ksm[wid*512]);          // K chunks 0-511
    gload16(Ksrc + (512 + wid*64 + l)*8,  &Ksm[4096 + wid*512]);   // K chunks 512-1023
    if (wid < 4){
      gload16(Ksrc + (1024 + wid*64 + l)*8, &Ksm[8192 + wid*512]); // K chunks 1024-1279
    } else {
      int cv = (wid-4)*64 + l;            // V chunks 0-255
      int d = cv >> 4, c16 = cv & 15;
      gload16(Vtb + (size_t)d*SEQ + k0 + ((c16 ^ (d & 15)) << 3), &Vtsm[(wid-4)*512]);
    }
    { int cv = 256 + wid*64 + l;          // V chunks 256-767
      int d = cv >> 4, c16 = cv & 15;
      gload16(Vtb + (size_t)d*SEQ + k0 + ((c16 ^ (d & 15)) << 3), &Vtsm[2048 + wid*512]); }
    { int cv = 768 + wid*64 + l;          // V chunks 768-1279
      int d = cv >> 4, c16 = cv & 15;
      gload16(Vtb + (size_t)d*SEQ + k0 + ((c16 ^ (d & 15)) << 3), &Vtsm[6144 + wid*512]); }
    __syncthreads();
    // S = K . Q^T (Q pre-scaled by 1/sqrt(80)*log2e in rope)
    f32x4 s[8];
    #pragma unroll
    for (int n=0;n<8;n++) s[n] = zf;
    #pragma unroll
    for (int c=0;c<3;c++){
      #pragma unroll
      for (int n=0;n<8;n++){
        bf16x8 kf = *(const bf16x8*)&Ksm[(n*16+lr)*80 + c*32 + lh*8];
        s[n] = __builtin_amdgcn_mfma_f32_16x16x32_bf16(kf, qf[c], s[n], 0,0,0);
      }
    }
    // online softmax in base-2; T13 defer-max (THR=8); tree-shaped max
    float pn[8];
    #pragma unroll
    for (int n=0;n<8;n++)
      pn[n] = fmaxf(fmaxf(s[n][0], s[n][1]), fmaxf(s[n][2], s[n][3]));
    float pm = fmaxf(fmaxf(fmaxf(pn[0],pn[1]), fmaxf(pn[2],pn[3])),
                     fmaxf(fmaxf(pn[4],pn[5]), fmaxf(pn[6],pn[7])));
    pm = fmaxf(pm, __shfl_xor(pm, 16));
    pm = fmaxf(pm, __shfl_xor(pm, 32));
    if (!__all(pm <= m + 8.f)){
      float mn = fmaxf(m, pm);
      float corr = exp2f(m - mn);
      #pragma unroll
      for (int r=0;r<4;r++) lsumv[r] *= corr;
      #pragma unroll
      for (int dt=0;dt<5;dt++)
        #pragma unroll
        for (int r=0;r<4;r++) o[dt][r] *= corr;
      m = mn;
    }
    #pragma unroll
    for (int n=0;n<8;n++)
      #pragma unroll
      for (int r=0;r<4;r++){
        float p = exp2f(s[n][r] - m);
        s[n][r] = p;
        lsumv[r] += p;
      }
    int w[16];
    #pragma unroll
    for (int n=0;n<8;n++){
      w[2*n]   = cvtpk_bf16(s[n][0], s[n][1]);
      w[2*n+1] = cvtpk_bf16(s[n][2], s[n][3]);
    }
    // PV: B-frag lane-local (keys pre-permuted per 64-block in Vt); V-frag XOR-swizzled
    #pragma unroll
    for (int kc=0;kc<4;kc++){
      union { bf16x8 v; int u[4]; } pf;
      pf.u[0] = w[4*kc+0]; pf.u[1] = w[4*kc+1];
      pf.u[2] = w[4*kc+2]; pf.u[3] = w[4*kc+3];
      #pragma unroll
      for (int dt=0;dt<5;dt++){
        int row = dt*16 + lr;
        bf16x8 vf = *(const bf16x8*)&Vtsm[row*128 + ((kc*32 + lh*8) ^ ((row & 15) << 3))];
        o[dt] = __builtin_amdgcn_mfma_f32_16x16x32_bf16(vf, pf.v, o[dt], 0,0,0);
      }
    }
    __syncthreads();
  }
  // epilogue: finish the deferred row-sum, then write out[q=lr][d = dt*16 + lh*4 + r]
  float t = (lsumv[0] + lsumv[1]) + (lsumv[2] + lsumv[3]);
  t += __shfl_xor(t, 16);
  t += __shfl_xor(t, 32);
  float inv = 1.0f / t;
  int qrow = q0 + wid*16 + lr;
  unsigned short* op = AO + (size_t)qrow*DIM + h*HD;
  #pragma unroll
  for (int dt=0;dt<5;dt++){
    unsigned int w0 = (unsigned int)cvtpk_bf16(o[dt][0]*inv, o[dt][1]*inv);
    unsigned int w1 = (unsigned int)cvtpk_bf16(o[dt][2]*inv, o[dt][3]*inv);
    uint2 ov = {w0, w1};
    *(uint2*)(op + dt*16 + lh*4) = ov;
  }
}

extern "C" void kernel_launch(void* const* d_in, const int* in_sizes, int n_in,
                              void* d_out, int out_size, void* d_ws, size_t ws_size,
                              hipStream_t stream){
  const float* hs    = (const float*)d_in[0];
  const float* cosb  = (const float*)d_in[1];
  const float* sinb  = (const float*)d_in[2];
  const float* wqkv  = (const float*)d_in[3];
  const float* bqkv  = (const float*)d_in[4];
  const float* wproj = (const float*)d_in[5];
  const float* bproj = (const float*)d_in[6];
  float* out = (float*)d_out;

  unsigned short* Abf    = (unsigned short*)d_ws;              // [SEQ][DIM] bf16
  unsigned short* Wqkvb  = Abf + (size_t)SEQ*DIM;              // [3*DIM][DIM] bf16
  unsigned short* Wprojb = Wqkvb + (size_t)3*DIM*DIM;          // [DIM][DIM] bf16
  unsigned short* QKVb   = Wprojb + (size_t)DIM*DIM;           // [3][NH][SEQ][HD] bf16 (V third unused)
  unsigned short* Vtb    = QKVb + (size_t)3*SEQ*DIM;           // [NH][HD][SEQ] bf16 (keys permuted per 64-block)
  unsigned short* AObf   = Abf;                                // reuse (A dead after gemm1)

  const int na = SEQ*DIM/4;            // 5,242,880 float4
  const int nb = 3*DIM*DIM/4;          // 1,228,800 float4
  const int nc = DIM*DIM/4;            //   409,600 float4
  pack3_kernel<<<(na+nb+nc)/256, 256, 0, stream>>>(hs, wqkv, wproj, Abf, Wqkvb, Wprojb, na, nb);

  gemm256_kernel<0><<<256, 512, 0, stream>>>(Abf, Wqkvb, bqkv,
                                             (void*)QKVb, Vtb, SEQ, 3*DIM, DIM);

  rope_kernel<<<(2*NH*SEQ*5)/256, 256, 0, stream>>>(QKVb, cosb, sinb);

  attn_kernel<<<NSEG*NH*(SEGL/128), 512, 0, stream>>>(QKVb, Vtb, AObf);

  gemm256_kernel<1><<<256, 512, 0, stream>>>(AObf, Wprojb, bproj,
                                             (void*)out, nullptr, SEQ, DIM, DIM);
}

// Round 16
// 446.704 us; speedup vs baseline: 1.0777x; 1.0777x over previous
//
#include <hip/hip_runtime.h>

#define SEQ 16384
#define DIM 1280
#define NH 16
#define HD 80
#define NSEG 16
#define SEGL 1024

typedef __attribute__((ext_vector_type(8))) short bf16x8;
typedef __attribute__((ext_vector_type(4))) float f32x4;

__device__ inline unsigned short f2bf(float f){
  unsigned int x = __builtin_bit_cast(unsigned int, f);
  unsigned int r = (x + 0x7FFFu + ((x >> 16) & 1u)) >> 16;
  return (unsigned short)r;
}
__device__ inline float bf2f(unsigned short u){
  unsigned int x = ((unsigned int)u) << 16;
  return __builtin_bit_cast(float, x);
}
__device__ inline int cvtpk_bf16(float lo, float hi){
  int r;
  asm("v_cvt_pk_bf16_f32 %0, %1, %2" : "=v"(r) : "v"(lo), "v"(hi));
  return r;
}

__device__ inline void gload16(const unsigned short* g, unsigned short* l){
  __builtin_amdgcn_global_load_lds((const __attribute__((address_space(1))) void*)g,
                                   (__attribute__((address_space(3))) void*)l, 16, 0, 0);
}

// ---------------- fused pack f32 -> bf16 for all three tensors (one launch) ----------
__global__ __launch_bounds__(256) void pack3_kernel(const float* __restrict__ a,
    const float* __restrict__ b, const float* __restrict__ c,
    unsigned short* __restrict__ da, unsigned short* __restrict__ db,
    unsigned short* __restrict__ dc, int na, int nb){
  int i = blockIdx.x * 256 + threadIdx.x;
  const float* s; unsigned short* d; int j;
  if (i < na){ s = a; d = da; j = i; }
  else if (i < na + nb){ s = b; d = db; j = i - na; }
  else { s = c; d = dc; j = i - na - nb; }
  float4 v = ((const float4*)s)[j];
  ushort4 o;
  o.x = f2bf(v.x); o.y = f2bf(v.y); o.z = f2bf(v.z); o.w = f2bf(v.w);
  ((ushort4*)d)[j] = o;
}

// ---------------- 256x256 8-phase GEMM  C = A * B^T (+bias), bf16 in ----------------
// Schedule as rounds 9-13, with bx held in registers across the tile (P3/P7 reloads
// deleted). EPI==0: scatter bf16 into QKV[3][NH][SEQ][HD], with the V third written
// directly to Vt[NH][HD][SEQ] with the attention key-permutation. EPI==1: f32 [M][N].
template<int EPI>
__global__ __launch_bounds__(512, 2) void gemm256_kernel(const unsigned short* __restrict__ A,
    const unsigned short* __restrict__ B, const float* __restrict__ bias,
    void* __restrict__ Cout, unsigned short* __restrict__ Vtg, int M, int N, int K){
  __shared__ __attribute__((aligned(16))) unsigned short As[2][16384];
  __shared__ __attribute__((aligned(16))) unsigned short Bs[2][16384];
  const int nwg = gridDim.x;
  int bid = blockIdx.x;
  int swz = (bid & 7) * (nwg >> 3) + (bid >> 3);   // nwg % 8 == 0 for our shapes
  const int ntn = N >> 8;
  const int tm = (swz / ntn) << 8;
  const int tn = (swz % ntn) << 8;
  const int tid = threadIdx.x;
  const int wid = tid >> 6, l = tid & 63;
  const int lr = l & 15, lh = l >> 4;
  const int wrM = (wid >> 2) << 7;   // 0 / 128
  const int wcN = (wid & 3) << 6;    // 0 / 64 / 128 / 192
  const int NITER = K >> 7;          // 2 K-tiles per iter

  const int srow = wid*8 + (l >> 3);
  const int scol = ((l & 7) ^ (l >> 3)) << 3;     // shorts
  const int sldsu = wid << 9;                     // shorts

  const unsigned short* Ag = A + (size_t)tm * K;
  const unsigned short* Bg = B + (size_t)tn * K;

  const int ck0 = (lh*8) ^ ((l & 7) << 3);
  const int ck1 = (32 + lh*8) ^ ((l & 7) << 3);
  const int raA = (wrM + lr) << 6;
  const int raB = (wcN + lr) << 6;

  f32x4 zf = {0.f,0.f,0.f,0.f};
  f32x4 acc[8][4];
  #pragma unroll
  for (int i=0;i<8;i++)
    #pragma unroll
    for (int j=0;j<4;j++) acc[i][j] = zf;

#define STAGE_A(tile, h, q) gload16(Ag + (size_t)((h)*128 + (q)*64 + srow)*K + ((tile)<<6) + scol, \
                                    &As[(tile)&1][(h)*8192 + (q)*4096 + sldsu])
#define STAGE_B(tile, h, q) gload16(Bg + (size_t)((h)*128 + (q)*64 + srow)*K + ((tile)<<6) + scol, \
                                    &Bs[(tile)&1][(h)*8192 + (q)*4096 + sldsu])
#define RD_A(b, MOFF) \
  _Pragma("unroll") \
  for (int mi=0; mi<4; ++mi){ \
    a[0][mi] = *(const bf16x8*)&As[b][raA + ((MOFF)+mi)*1024 + ck0]; \
    a[1][mi] = *(const bf16x8*)&As[b][raA + ((MOFF)+mi)*1024 + ck1]; }
#define RD_B(b, NOFF, BREG) \
  _Pragma("unroll") \
  for (int nj=0; nj<2; ++nj){ \
    BREG[0][nj] = *(const bf16x8*)&Bs[b][raB + ((NOFF)+nj)*1024 + ck0]; \
    BREG[1][nj] = *(const bf16x8*)&Bs[b][raB + ((NOFF)+nj)*1024 + ck1]; }
#define BAR() __builtin_amdgcn_s_barrier();
#define QMFMA(MB, NB, BREG) \
  __builtin_amdgcn_s_setprio(1); \
  _Pragma("unroll") \
  for (int mi=0; mi<4; ++mi){ \
    _Pragma("unroll") \
    for (int nj=0; nj<2; ++nj){ \
      acc[(MB)+mi][(NB)+nj] = __builtin_amdgcn_mfma_f32_16x16x32_bf16(a[0][mi], BREG[0][nj], acc[(MB)+mi][(NB)+nj], 0,0,0); \
      acc[(MB)+mi][(NB)+nj] = __builtin_amdgcn_mfma_f32_16x16x32_bf16(a[1][mi], BREG[1][nj], acc[(MB)+mi][(NB)+nj], 0,0,0); \
    } \
  } \
  __builtin_amdgcn_s_setprio(0); \
  __builtin_amdgcn_s_barrier();

  // prologue: stage tiles 0 and 1 (16 loads); drain tile 0, keep tile 1 in flight
  #pragma unroll
  for (int q=0;q<2;q++){ STAGE_A(0,0,q); }
  #pragma unroll
  for (int q=0;q<2;q++){ STAGE_A(0,1,q); }
  #pragma unroll
  for (int q=0;q<2;q++){ STAGE_B(0,0,q); }
  #pragma unroll
  for (int q=0;q<2;q++){ STAGE_B(0,1,q); }
  #pragma unroll
  for (int q=0;q<2;q++){ STAGE_B(1,0,q); }
  #pragma unroll
  for (int q=0;q<2;q++){ STAGE_B(1,1,q); }
  #pragma unroll
  for (int q=0;q<2;q++){ STAGE_A(1,0,q); }
  #pragma unroll
  for (int q=0;q<2;q++){ STAGE_A(1,1,q); }
  asm volatile("s_waitcnt vmcnt(8)" ::: "memory");
  __builtin_amdgcn_s_barrier();

  for (int i=0; i<NITER; ++i){
    const int T = 2*i;
    const bool st = (i+1 < NITER);
    bf16x8 a[2][4], bx[2][2], by[2][2];

    // ---- P0: read bx,a(m0-3) of buf0; MFMA m0-3 x n0-1
    RD_B(0, 0, bx); RD_A(0, 0);
    BAR(); QMFMA(0, 0, bx);

    // ---- P1: read by(n2-3); MFMA m0-3 x n2-3
    RD_B(0, 2, by);
    BAR(); QMFMA(0, 2, by);

    // ---- P2: read a(m4-7); stage Bh0(T+2); MFMA m4-7 x n2-3
    RD_A(0, 4);
    if (st){ STAGE_B(T+2, 0, 0); STAGE_B(T+2, 0, 1); }
    BAR(); QMFMA(4, 2, by);

    // ---- P3: stage Bh1(T+2), Ah0(T+2); vmcnt drains T+1; MFMA m4-7 x n0-1 (bx held)
    if (st){
      STAGE_B(T+2, 1, 0); STAGE_B(T+2, 1, 1);
      STAGE_A(T+2, 0, 0); STAGE_A(T+2, 0, 1);
      asm volatile("s_waitcnt vmcnt(6)" ::: "memory");
    } else {
      asm volatile("s_waitcnt vmcnt(0)" ::: "memory");
    }
    BAR(); QMFMA(4, 0, bx);

    // ---- P4: read bx,a(m0-3) of buf1; stage Ah1(T+2); MFMA m0-3 x n0-1
    RD_B(1, 0, bx); RD_A(1, 0);
    if (st){ STAGE_A(T+2, 1, 0); STAGE_A(T+2, 1, 1); }
    BAR(); QMFMA(0, 0, bx);

    // ---- P5: read by; MFMA m0-3 x n2-3
    RD_B(1, 2, by);
    BAR(); QMFMA(0, 2, by);

    // ---- P6: read a(m4-7); stage Bh0+Bh1(T+3); MFMA m4-7 x n2-3
    RD_A(1, 4);
    if (st){ STAGE_B(T+3, 0, 0); STAGE_B(T+3, 0, 1); STAGE_B(T+3, 1, 0); STAGE_B(T+3, 1, 1); }
    BAR(); QMFMA(4, 2, by);

    // ---- P7: stage Ah0+Ah1(T+3); vmcnt drains T+2; MFMA m4-7 x n0-1 (bx held)
    if (st){
      STAGE_A(T+3, 0, 0); STAGE_A(T+3, 0, 1); STAGE_A(T+3, 1, 0); STAGE_A(T+3, 1, 1);
      asm volatile("s_waitcnt vmcnt(8)" ::: "memory");
    }
    BAR(); QMFMA(4, 0, bx);
  }

#undef STAGE_A
#undef STAGE_B
#undef RD_A
#undef RD_B
#undef BAR
#undef QMFMA

  // epilogue
  #pragma unroll
  for (int nj=0;nj<4;nj++){
    int col = tn + wcN + nj*16 + lr;
    float bv = bias[col];
    if (EPI == 0){
      int which = col / DIM;           // uniform within the 16-col group
      int rem = col - which*DIM;
      int hh = rem / HD;
      int d = rem - hh*HD;
      if (which == 2){
        // fused V-transpose: write Vt[hh][d][s] with key-permutation per 64-block
        unsigned short* Vd = Vtg + ((size_t)hh * HD + d) * SEQ;
        #pragma unroll
        for (int mi=0;mi<8;mi++){
          int row0 = tm + wrM + mi*16 + lh*4;
          int g = (row0 >> 2) & 15;
          int pg = ((g>>3)<<3) + ((g&3)<<1) + ((g>>2)&1);
          int s = (row0 & ~63) + pg*4;
          unsigned int w0 = (unsigned int)cvtpk_bf16(acc[mi][nj][0]+bv, acc[mi][nj][1]+bv);
          unsigned int w1 = (unsigned int)cvtpk_bf16(acc[mi][nj][2]+bv, acc[mi][nj][3]+bv);
          uint2 ov = {w0, w1};
          *(uint2*)(Vd + s) = ov;
        }
      } else {
        unsigned short* Q = (unsigned short*)Cout;
        size_t base = (size_t)(which*NH + hh) * SEQ;
        #pragma unroll
        for (int mi=0;mi<8;mi++){
          #pragma unroll
          for (int r=0;r<4;r++){
            int row = tm + wrM + mi*16 + lh*4 + r;
            Q[(base + row)*HD + d] = f2bf(acc[mi][nj][r] + bv);
          }
        }
      }
    } else {
      float* C = (float*)Cout;
      #pragma unroll
      for (int mi=0;mi<8;mi++){
        #pragma unroll
        for (int r=0;r<4;r++){
          int row = tm + wrM + mi*16 + lh*4 + r;
          C[(size_t)row*N + col] = acc[mi][nj][r] + bv;
        }
      }
    }
  }
}

// ---------------- in-place RoPE, VECTORIZED: thread handles 8 (d, d+40) pairs ----------
// Q part pre-scaled by 1/sqrt(80)*log2(e). cos[s][d] == cos[s][d+40] by construction.
__global__ __launch_bounds__(256) void rope_kernel(unsigned short* __restrict__ QKV,
    const float* __restrict__ cosb, const float* __restrict__ sinb){
  unsigned int gid = blockIdx.x * 256 + threadIdx.x;   // 2*NH*SEQ*5 total
  int pc = gid % 5;
  unsigned int row = gid / 5;        // [(which*NH+h)*SEQ + s]
  int s = row % SEQ;
  int pd = pc * 8;
  float f = (row < (unsigned)(NH*SEQ)) ? (0.111803398874989485f * 1.4426950408889634f) : 1.0f;
  unsigned short* p = QKV + (size_t)row * HD;
  union { uint4 u4; unsigned short h[8]; } x1, x2, y1, y2;
  x1.u4 = *(const uint4*)(p + pd);
  x2.u4 = *(const uint4*)(p + pd + 40);
  float4 c0 = *(const float4*)(cosb + s*HD + pd);
  float4 c1 = *(const float4*)(cosb + s*HD + pd + 4);
  float4 s0 = *(const float4*)(sinb + s*HD + pd);
  float4 s1 = *(const float4*)(sinb + s*HD + pd + 4);
  float cc[8] = {c0.x,c0.y,c0.z,c0.w,c1.x,c1.y,c1.z,c1.w};
  float ss[8] = {s0.x,s0.y,s0.z,s0.w,s1.x,s1.y,s1.z,s1.w};
  #pragma unroll
  for (int j=0;j<8;j++){
    float a = bf2f(x1.h[j]), b = bf2f(x2.h[j]);
    y1.h[j] = f2bf((a*cc[j] - b*ss[j])*f);
    y2.h[j] = f2bf((b*cc[j] + a*ss[j])*f);
  }
  *(uint4*)(p + pd)      = y1.u4;
  *(uint4*)(p + pd + 40) = y2.u4;
}

// ---------------- flash attention, swapped operands; 8 waves x 16 q-rows = 128 q/block ----
// KVBLK=128: K staged PACKED [128][80] (straight contiguous copy); V staged [80][128]
// from pre-permuted Vt, XOR-swizzled at 16B granularity (c16 ^ (d&15), both sides).
// S = mfma(K, Q^T) -> C[key, q]; O = mfma(V^T, P^T) -> C[d, q]  (lane owns q-row lr)
// XCD-grouped block decode; deferred cross-lane row-sum.
__global__ __launch_bounds__(512) void attn_kernel(const unsigned short* __restrict__ QKV,
                                                   const unsigned short* __restrict__ Vt,
                                                   unsigned short* __restrict__ AO){
  int bid = blockIdx.x;
  int qt  = (bid >> 3) & 7;
  int g   = (bid & 7) * 32 + (bid >> 6);   // (seg,h) group, constant per XCD slot
  int h   = g & 15;
  int seg = g >> 4;
  int tid = threadIdx.x, wid = tid >> 6, l = tid & 63;
  int lr = l & 15, lh = l >> 4;
  const unsigned short* Qb = QKV + (size_t)(0*NH + h) * SEQ * HD;
  const unsigned short* Kb = QKV + (size_t)(1*NH + h) * SEQ * HD;
  const unsigned short* Vtb = Vt + (size_t)h * HD * SEQ;
  int q0 = seg*SEGL + qt*128;
  __shared__ __attribute__((aligned(16))) unsigned short Ksm[10240];  // [128][80] packed
  __shared__ __attribute__((aligned(16))) unsigned short Vtsm[10240]; // [80][128] swizzled
  bf16x8 qf[3];
  {
    const unsigned short* qp = Qb + (size_t)(q0 + wid*16 + lr) * HD;
    #pragma unroll
    for (int c=0;c<3;c++){
      int d0 = c*32 + lh*8;
      bf16x8 z = {0,0,0,0,0,0,0,0};
      qf[c] = (d0 < HD) ? *(const bf16x8*)(qp + d0) : z;
    }
  }
  f32x4 zf = {0.f,0.f,0.f,0.f};
  f32x4 o[5];
  #pragma unroll
  for (int dt=0;dt<5;dt++) o[dt] = zf;
  f32x4 lsumv = zf;
  float m = -1e30f;
  for (int kt=0; kt<8; kt++){
    int k0 = seg*SEGL + kt*128;
    const unsigned short* Ksrc = Kb + (size_t)k0 * HD;   // 128*80 shorts contiguous
    gload16(Ksrc + (wid*64 + l)*8,        &Ksm[wid*512]);          // K chunks 0-511
    gload16(Ksrc + (512 + wid*64 + l)*8,  &Ksm[4096 + wid*512]);   // K chunks 512-1023
    if (wid < 4){
      gload16(Ksrc + (1024 + wid*64 + l)*8, &Ksm[8192 + wid*512]); // K chunks 1024-1279
    } else {
      int cv = (wid-4)*64 + l;            // V chunks 0-255
      int d = cv >> 4, c16 = cv & 15;
      gload16(Vtb + (size_t)d*SEQ + k0 + ((c16 ^ (d & 15)) << 3), &Vtsm[(wid-4)*512]);
    }
    { int cv = 256 + wid*64 + l;          // V chunks 256-767
      int d = cv >> 4, c16 = cv & 15;
      gload16(Vtb + (size_t)d*SEQ + k0 + ((c16 ^ (d & 15)) << 3), &Vtsm[2048 + wid*512]); }
    { int cv = 768 + wid*64 + l;          // V chunks 768-1279
      int d = cv >> 4, c16 = cv & 15;
      gload16(Vtb + (size_t)d*SEQ + k0 + ((c16 ^ (d & 15)) << 3), &Vtsm[6144 + wid*512]); }
    __syncthreads();
    // S = K . Q^T (Q pre-scaled by 1/sqrt(80)*log2e in rope)
    f32x4 s[8];
    #pragma unroll
    for (int n=0;n<8;n++) s[n] = zf;
    #pragma unroll
    for (int c=0;c<3;c++){
      #pragma unroll
      for (int n=0;n<8;n++){
        bf16x8 kf = *(const bf16x8*)&Ksm[(n*16+lr)*80 + c*32 + lh*8];
        s[n] = __builtin_amdgcn_mfma_f32_16x16x32_bf16(kf, qf[c], s[n], 0,0,0);
      }
    }
    // online softmax in base-2; T13 defer-max (THR=8); tree-shaped max
    float pn[8];
    #pragma unroll
    for (int n=0;n<8;n++)
      pn[n] = fmaxf(fmaxf(s[n][0], s[n][1]), fmaxf(s[n][2], s[n][3]));
    float pm = fmaxf(fmaxf(fmaxf(pn[0],pn[1]), fmaxf(pn[2],pn[3])),
                     fmaxf(fmaxf(pn[4],pn[5]), fmaxf(pn[6],pn[7])));
    pm = fmaxf(pm, __shfl_xor(pm, 16));
    pm = fmaxf(pm, __shfl_xor(pm, 32));
    if (!__all(pm <= m + 8.f)){
      float mn = fmaxf(m, pm);
      float corr = exp2f(m - mn);
      #pragma unroll
      for (int r=0;r<4;r++) lsumv[r] *= corr;
      #pragma unroll
      for (int dt=0;dt<5;dt++)
        #pragma unroll
        for (int r=0;r<4;r++) o[dt][r] *= corr;
      m = mn;
    }
    #pragma unroll
    for (int n=0;n<8;n++)
      #pragma unroll
      for (int r=0;r<4;r++){
        float p = exp2f(s[n][r] - m);
        s[n][r] = p;
        lsumv[r] += p;
      }
    int w[16];
    #pragma unroll
    for (int n=0;n<8;n++){
      w[2*n]   = cvtpk_bf16(s[n][0], s[n][1]);
      w[2*n+1] = cvtpk_bf16(s[n][2], s[n][3]);
    }
    // PV: B-frag lane-local (keys pre-permuted per 64-block in Vt); V-frag XOR-swizzled
    #pragma unroll
    for (int kc=0;kc<4;kc++){
      union { bf16x8 v; int u[4]; } pf;
      pf.u[0] = w[4*kc+0]; pf.u[1] = w[4*kc+1];
      pf.u[2] = w[4*kc+2]; pf.u[3] = w[4*kc+3];
      #pragma unroll
      for (int dt=0;dt<5;dt++){
        int row = dt*16 + lr;
        bf16x8 vf = *(const bf16x8*)&Vtsm[row*128 + ((kc*32 + lh*8) ^ ((row & 15) << 3))];
        o[dt] = __builtin_amdgcn_mfma_f32_16x16x32_bf16(vf, pf.v, o[dt], 0,0,0);
      }
    }
    __syncthreads();
  }
  // epilogue: finish the deferred row-sum, then write out[q=lr][d = dt*16 + lh*4 + r]
  float t = (lsumv[0] + lsumv[1]) + (lsumv[2] + lsumv[3]);
  t += __shfl_xor(t, 16);
  t += __shfl_xor(t, 32);
  float inv = 1.0f / t;
  int qrow = q0 + wid*16 + lr;
  unsigned short* op = AO + (size_t)qrow*DIM + h*HD;
  #pragma unroll
  for (int dt=0;dt<5;dt++){
    unsigned int w0 = (unsigned int)cvtpk_bf16(o[dt][0]*inv, o[dt][1]*inv);
    unsigned int w1 = (unsigned int)cvtpk_bf16(o[dt][2]*inv, o[dt][3]*inv);
    uint2 ov = {w0, w1};
    *(uint2*)(op + dt*16 + lh*4) = ov;
  }
}

extern "C" void kernel_launch(void* const* d_in, const int* in_sizes, int n_in,
                              void* d_out, int out_size, void* d_ws, size_t ws_size,
                              hipStream_t stream){
  const float* hs    = (const float*)d_in[0];
  const float* cosb  = (const float*)d_in[1];
  const float* sinb  = (const float*)d_in[2];
  const float* wqkv  = (const float*)d_in[3];
  const float* bqkv  = (const float*)d_in[4];
  const float* wproj = (const float*)d_in[5];
  const float* bproj = (const float*)d_in[6];
  float* out = (float*)d_out;

  unsigned short* Abf    = (unsigned short*)d_ws;              // [SEQ][DIM] bf16
  unsigned short* Wqkvb  = Abf + (size_t)SEQ*DIM;              // [3*DIM][DIM] bf16
  unsigned short* Wprojb = Wqkvb + (size_t)3*DIM*DIM;          // [DIM][DIM] bf16
  unsigned short* QKVb   = Wprojb + (size_t)DIM*DIM;           // [3][NH][SEQ][HD] bf16 (V third unused)
  unsigned short* Vtb    = QKVb + (size_t)3*SEQ*DIM;           // [NH][HD][SEQ] bf16 (keys permuted per 64-block)
  unsigned short* AObf   = Abf;                                // reuse (A dead after gemm1)

  const int na = SEQ*DIM/4;            // 5,242,880 float4
  const int nb = 3*DIM*DIM/4;          // 1,228,800 float4
  const int nc = DIM*DIM/4;            //   409,600 float4
  pack3_kernel<<<(na+nb+nc)/256, 256, 0, stream>>>(hs, wqkv, wproj, Abf, Wqkvb, Wprojb, na, nb);

  gemm256_kernel<0><<<(SEQ/256)*((3*DIM)/256), 512, 0, stream>>>(Abf, Wqkvb, bqkv,
                                                                 (void*)QKVb, Vtb, SEQ, 3*DIM, DIM);

  rope_kernel<<<(2*NH*SEQ*5)/256, 256, 0, stream>>>(QKVb, cosb, sinb);

  attn_kernel<<<NSEG*NH*(SEGL/128), 512, 0, stream>>>(QKVb, Vtb, AObf);

  gemm256_kernel<1><<<(SEQ/256)*(DIM/256), 512, 0, stream>>>(AObf, Wprojb, bproj,
                                                             (void*)out, nullptr, SEQ, DIM, DIM);
}